// Round 5
// baseline (334.030 us; speedup 1.0000x reference)
//
#include <hip/hip_runtime.h>

#define I_LEN 1024
#define S_LEN 4096

typedef float f32x4 __attribute__((ext_vector_type(4)));

__device__ __forceinline__ unsigned int f2h(float f) {
  _Float16 h = (_Float16)f; unsigned short u;
  __builtin_memcpy(&u, &h, 2); return (unsigned int)u;
}
__device__ __forceinline__ float h2f(unsigned int u) {
  unsigned short s = (unsigned short)u; _Float16 h;
  __builtin_memcpy(&h, &s, 2); return (float)h;
}

// ---------------------------------------------------------------------------
// K1a: LN + k/v + q-partials. Lane-dense layout: wave = 64 consecutive
// columns, thread = ONE column x 16 s-rows. All stores full-line dense
// (kvS: 256 B/instr -> no partial-line RMW; R2 measured 2x write amp with
// the old 16-col layout). 4 half-tiles of 4 rows, double-buffered prefetch
// (next half-tile's 12 loads in flight during current compute).
// Grid 1024 = 4 col-groups x 256 s-blocks. 256 thr.
// ---------------------------------------------------------------------------
__global__ __launch_bounds__(256, 2) void msa_k1a(
    const float* __restrict__ m, const float* __restrict__ mask,
    const float* __restrict__ lng, const float* __restrict__ lnb,
    const float* __restrict__ Wk, const float* __restrict__ Wv,
    unsigned int* __restrict__ kvS, float* __restrict__ qpart)
{
  const int b  = blockIdx.x;          // 1024 = 4 cg x 256 sb
  const int cg = b & 3;
  const int sb = b >> 2;
  const int i  = cg * 256 + threadIdx.x;   // lane-consecutive columns
  const int s0 = sb * 16;

  // uniform folded weights (SGPR-sourced)
  float swk = 0.f, swv = 0.f, kb = 0.f, vb = 0.f;
#pragma unroll
  for (int c = 0; c < 8; ++c) {
    swk = fmaf(lng[c], Wk[c], swk);  swv = fmaf(lng[c], Wv[c], swv);
    kb  = fmaf(lnb[c], Wk[c], kb);   vb  = fmaf(lnb[c], Wv[c], vb);
  }

  float qnx[8] = {0,0,0,0,0,0,0,0};
  float qd = 0.f;

  float4 A0[4], B0[4]; float M0[4];   // buffer 0
  float4 A1[4], B1[4]; float M1[4];   // buffer 1

#define K1A_LOAD(Ab, Bb, Mb, HT)                                         \
  _Pragma("unroll")                                                      \
  for (int rr = 0; rr < 4; ++rr) {                                       \
    const size_t base = (size_t)((s0 + (HT) * 4 + rr) * I_LEN + i);      \
    const float4* mp = (const float4*)(m + base * 8);                    \
    Ab[rr] = mp[0]; Bb[rr] = mp[1]; Mb[rr] = mask[base];                 \
  }

#define K1A_COMP(Ab, Bb, Mb, HT)                                         \
  _Pragma("unroll")                                                      \
  for (int rr = 0; rr < 4; ++rr) {                                       \
    const size_t base = (size_t)((s0 + (HT) * 4 + rr) * I_LEN + i);      \
    float x[8] = {Ab[rr].x, Ab[rr].y, Ab[rr].z, Ab[rr].w,                \
                  Bb[rr].x, Bb[rr].y, Bb[rr].z, Bb[rr].w};               \
    const float mk = Mb[rr];                                             \
    float su = 0.f, s2 = 0.f;                                            \
    _Pragma("unroll")                                                    \
    for (int c = 0; c < 8; ++c) { su += x[c]; s2 = fmaf(x[c], x[c], s2); } \
    const float mu   = su * 0.125f;                                      \
    const float var  = s2 * 0.125f - mu * mu;                            \
    const float rstd = rsqrtf(var + 1e-5f);                              \
    float dk = 0.f, dv = 0.f;                                            \
    _Pragma("unroll")                                                    \
    for (int c = 0; c < 8; ++c) {                                        \
      const float xg = x[c] * lng[c];                                    \
      dk = fmaf(xg, Wk[c], dk);                                          \
      dv = fmaf(xg, Wv[c], dv);                                          \
      x[c] = xg;                                                         \
    }                                                                    \
    const float kk = fmaf(rstd, fmaf(-mu, swk, dk), kb);                 \
    const float vv = fmaf(rstd, fmaf(-mu, swv, dv), vb);                 \
    kvS[base] = (mk > 0.5f) ? ((f2h(kk) << 16) | f2h(vv)) : 0xFFFFFFFFu; \
    const float mr  = mk * rstd;                                         \
    const float mmr = -mu * mr;                                          \
    _Pragma("unroll")                                                    \
    for (int c = 0; c < 8; ++c)                                          \
      qnx[c] = fmaf(x[c], mr, fmaf(lng[c], mmr, qnx[c]));                \
    qd += mk;                                                            \
  }

  K1A_LOAD(A0, B0, M0, 0)
  K1A_LOAD(A1, B1, M1, 1)
  __builtin_amdgcn_sched_barrier(0);
  K1A_COMP(A0, B0, M0, 0)
  K1A_LOAD(A0, B0, M0, 2)
  __builtin_amdgcn_sched_barrier(0);
  K1A_COMP(A1, B1, M1, 1)
  K1A_LOAD(A1, B1, M1, 3)
  __builtin_amdgcn_sched_barrier(0);
  K1A_COMP(A0, B0, M0, 2)
  __builtin_amdgcn_sched_barrier(0);
  K1A_COMP(A1, B1, M1, 3)

  // per-thread partials: contiguous 48 B/lane
  float4* pp = (float4*)(qpart + ((size_t)sb * I_LEN + i) * 12);
  pp[0] = make_float4(qnx[0], qnx[1], qnx[2], qnx[3]);
  pp[1] = make_float4(qnx[4], qnx[5], qnx[6], qnx[7]);
  pp[2] = make_float4(qd, 0.f, 0.f, 0.f);
#undef K1A_LOAD
#undef K1A_COMP
}

// ---------------------------------------------------------------------------
// K1b: reduce qpart (256 partials/column) -> pooled q -> qtab[i][8].
// 256 blocks x 64 threads: wave = 4 columns x 16 slices.
// ---------------------------------------------------------------------------
__global__ __launch_bounds__(64) void msa_k1b(
    const float* __restrict__ lnb, const float* __restrict__ Wq,
    const float* __restrict__ qpart, float* __restrict__ qtab)
{
  const int l  = threadIdx.x;
  const int i  = blockIdx.x * 4 + (l & 3);
  const int sl = l >> 2;             // 16 slices
  float acc[9] = {0,0,0,0,0,0,0,0,0};
#pragma unroll
  for (int it = 0; it < 16; ++it) {
    const int sb = sl + it * 16;
    const float4* p = (const float4*)(qpart + ((size_t)sb * I_LEN + i) * 12);
    const float4 a = p[0], b4 = p[1], c4 = p[2];
    acc[0] += a.x;  acc[1] += a.y;  acc[2] += a.z;  acc[3] += a.w;
    acc[4] += b4.x; acc[5] += b4.y; acc[6] += b4.z; acc[7] += b4.w;
    acc[8] += c4.x;
  }
#pragma unroll
  for (int q = 0; q < 9; ++q) {
    float x = acc[q];
    x += __shfl_xor(x, 4);
    x += __shfl_xor(x, 8);
    x += __shfl_xor(x, 16);
    x += __shfl_xor(x, 32);
    acc[q] = x;
  }
  if (l < 4) {
    const float d   = acc[8];
    const float inv = 1.0f / (d + 1e-5f);
    float qs[8];
#pragma unroll
    for (int c = 0; c < 8; ++c) qs[c] = (acc[c] + lnb[c] * d) * inv;
    float qv[8];
#pragma unroll
    for (int h = 0; h < 8; ++h) {
      float v = 0.f;
#pragma unroll
      for (int c = 0; c < 8; ++c) v = fmaf(qs[c], Wq[c * 8 + h], v);
      qv[h] = v;                      // c_h^-0.5 == 1
    }
    float4* qp = (float4*)(qtab + (size_t)i * 8);
    qp[0] = make_float4(qv[0], qv[1], qv[2], qv[3]);
    qp[1] = make_float4(qv[4], qv[5], qv[6], qv[7]);
  }
}

// ---------------------------------------------------------------------------
// K1c: softmax partial sums over kvS. Lane-dense like K1a: thread = one
// column x 16 rows; all 16 kvS loads batched up front (dense 256 B/instr).
// Writes spart[sb][i][16] = {se[8], sv[8]} per thread (no shuffles).
// ---------------------------------------------------------------------------
__global__ __launch_bounds__(256, 2) void msa_k1c(
    const unsigned int* __restrict__ kvS, const float* __restrict__ qtab,
    float* __restrict__ spart)
{
  const int b  = blockIdx.x;          // 1024 = 4 cg x 256 sb
  const int cg = b & 3;
  const int sb = b >> 2;
  const int i  = cg * 256 + threadIdx.x;
  const int s0 = sb * 16;

  const float4* qp = (const float4*)(qtab + (size_t)i * 8);
  const float4 q0 = qp[0], q1 = qp[1];
  const float qh[8] = {q0.x, q0.y, q0.z, q0.w, q1.x, q1.y, q1.z, q1.w};

  unsigned int W[16];
#pragma unroll
  for (int r = 0; r < 16; ++r)
    W[r] = kvS[(size_t)((s0 + r) * I_LEN + i)];
  __builtin_amdgcn_sched_barrier(0);

  float se[8] = {0,0,0,0,0,0,0,0};
  float sv[8] = {0,0,0,0,0,0,0,0};
#pragma unroll
  for (int r = 0; r < 16; ++r) {
    const unsigned int wv = W[r];
    const bool on = (wv != 0xFFFFFFFFu);
    const float kk = h2f(wv >> 16);
    const float vv = on ? h2f(wv & 0xFFFFu) : 0.0f;
#pragma unroll
    for (int h = 0; h < 8; ++h) {
      const float e = on ? __expf(qh[h] * kk) : 0.0f;
      se[h] += e;
      sv[h] = fmaf(e, vv, sv[h]);
    }
  }
  float4* pp = (float4*)(spart + ((size_t)sb * I_LEN + i) * 16);
  pp[0] = make_float4(se[0], se[1], se[2], se[3]);
  pp[1] = make_float4(se[4], se[5], se[6], se[7]);
  pp[2] = make_float4(sv[0], sv[1], sv[2], sv[3]);
  pp[3] = make_float4(sv[4], sv[5], sv[6], sv[7]);
}

// ---------------------------------------------------------------------------
// K1d: reduce spart (256 partials/column) -> o_tab[i][8] = sum(e*v)/sum(e).
// ---------------------------------------------------------------------------
__global__ __launch_bounds__(64) void msa_k1d(
    const float* __restrict__ spart, float* __restrict__ o_tab)
{
  const int l  = threadIdx.x;
  const int i  = blockIdx.x * 4 + (l & 3);
  const int sl = l >> 2;
  float acc[16] = {0,0,0,0,0,0,0,0,0,0,0,0,0,0,0,0};
#pragma unroll
  for (int it = 0; it < 16; ++it) {
    const int sb = sl + it * 16;
    const float4* p = (const float4*)(spart + ((size_t)sb * I_LEN + i) * 16);
    const float4 a = p[0], b4 = p[1], c4 = p[2], d4 = p[3];
    acc[0]  += a.x;  acc[1]  += a.y;  acc[2]  += a.z;  acc[3]  += a.w;
    acc[4]  += b4.x; acc[5]  += b4.y; acc[6]  += b4.z; acc[7]  += b4.w;
    acc[8]  += c4.x; acc[9]  += c4.y; acc[10] += c4.z; acc[11] += c4.w;
    acc[12] += d4.x; acc[13] += d4.y; acc[14] += d4.z; acc[15] += d4.w;
  }
#pragma unroll
  for (int q = 0; q < 16; ++q) {
    float x = acc[q];
    x += __shfl_xor(x, 4);
    x += __shfl_xor(x, 8);
    x += __shfl_xor(x, 16);
    x += __shfl_xor(x, 32);
    acc[q] = x;
  }
  if (l < 4) {
    float4* op = (float4*)(o_tab + (size_t)i * 8);
    op[0] = make_float4(acc[8]  / acc[0], acc[9]  / acc[1],
                        acc[10] / acc[2], acc[11] / acc[3]);
    op[1] = make_float4(acc[12] / acc[4], acc[13] / acc[5],
                        acc[14] / acc[6], acc[15] / acc[7]);
  }
}

// ---------------------------------------------------------------------------
// K2: re-read m (L3-warm), recompute LN + gates, apply attention, write out
// non-temporal. VALU cut: sigmoid-divide now uses v_rcp
// (__builtin_amdgcn_rcpf) instead of the exact-division sequence the
// compiler emits for '/' (~10 instrs incl. quarter-rate, x8 per point).
// ---------------------------------------------------------------------------
__global__ __launch_bounds__(256, 2) void msa_k2(
    const float* __restrict__ m,
    const float* __restrict__ lng, const float* __restrict__ lnb,
    const float* __restrict__ Wg, const float* __restrict__ bg,
    const float* __restrict__ Wo, const float* __restrict__ bo,
    const float* __restrict__ o_tab, float* __restrict__ out)
{
  const int tid = blockIdx.x * 256 + threadIdx.x;   // 524288 threads
  const int i = tid & (I_LEN - 1);

  // uniform derived vectors (SGPR-sourced weights)
  float sgv[8], tbv[8];
#pragma unroll
  for (int h = 0; h < 8; ++h) {
    float s = 0.f, tb = bg[h];
#pragma unroll
    for (int c = 0; c < 8; ++c) {
      s  = fmaf(lng[c], Wg[c * 8 + h], s);
      tb = fmaf(lnb[c], Wg[c * 8 + h], tb);
    }
    sgv[h] = s; tbv[h] = tb;
  }

  const float4* op = (const float4*)(o_tab + (size_t)i * 8);
  const float4 o1 = op[0], o2 = op[1];
  const float A[8] = {o1.x, o1.y, o1.z, o1.w, o2.x, o2.y, o2.z, o2.w};

#pragma unroll
  for (int g2 = 0; g2 < 2; ++g2) {
    float4 LO[4], HI[4];
#pragma unroll
    for (int r = 0; r < 4; ++r) {
      const size_t p = (size_t)tid + (size_t)(g2 * 4 + r) * 524288;
      const float4* mp = (const float4*)(m + p * 8);
      LO[r] = mp[0]; HI[r] = mp[1];
    }
    __builtin_amdgcn_sched_barrier(0);
#pragma unroll
    for (int r = 0; r < 4; ++r) {
      const size_t p = (size_t)tid + (size_t)(g2 * 4 + r) * 524288;
      float x[8] = {LO[r].x, LO[r].y, LO[r].z, LO[r].w,
                    HI[r].x, HI[r].y, HI[r].z, HI[r].w};
      float su = 0.f, s2 = 0.f;
#pragma unroll
      for (int c = 0; c < 8; ++c) { su += x[c]; s2 = fmaf(x[c], x[c], s2); }
      const float mu   = su * 0.125f;
      const float var  = s2 * 0.125f - mu * mu;
      const float rstd = rsqrtf(var + 1e-5f);
#pragma unroll
      for (int c = 0; c < 8; ++c) x[c] *= lng[c];
      float acc[8];
#pragma unroll
      for (int c = 0; c < 8; ++c) acc[c] = bo[c];
#pragma unroll
      for (int h = 0; h < 8; ++h) {
        float d = 0.f;
#pragma unroll
        for (int c = 0; c < 8; ++c) d = fmaf(x[c], Wg[c * 8 + h], d);
        const float gl = fmaf(rstd, fmaf(-mu, sgv[h], d), tbv[h]);
        const float gv = A[h] * __builtin_amdgcn_rcpf(1.0f + __expf(-gl));
#pragma unroll
        for (int c = 0; c < 8; ++c) acc[c] = fmaf(gv, Wo[h * 8 + c], acc[c]);
      }
      f32x4* outp = (f32x4*)(out + p * 8);
      f32x4 r0 = {acc[0], acc[1], acc[2], acc[3]};
      f32x4 r1 = {acc[4], acc[5], acc[6], acc[7]};
      __builtin_nontemporal_store(r0, outp);
      __builtin_nontemporal_store(r1, outp + 1);
    }
  }
}

extern "C" void kernel_launch(void* const* d_in, const int* in_sizes, int n_in,
                              void* d_out, int out_size, void* d_ws, size_t ws_size,
                              hipStream_t stream) {
  const float* m    = (const float*)d_in[0];
  const float* mask = (const float*)d_in[1];
  const float* lng  = (const float*)d_in[2];
  const float* lnb  = (const float*)d_in[3];
  const float* Wq   = (const float*)d_in[4];
  const float* Wk   = (const float*)d_in[5];
  const float* Wv   = (const float*)d_in[6];
  const float* Wg   = (const float*)d_in[7];
  const float* bg   = (const float*)d_in[8];
  const float* Wo   = (const float*)d_in[9];
  const float* bo   = (const float*)d_in[10];
  float* out = (float*)d_out;

  // ws layout: o_tab 32KB @0 | qtab 32KB @64K | kvS 16.8MB @1M |
  //            qpart 12.6MB @32M | spart 16.8MB @48M
  char* ws = (char*)d_ws;
  float*        o_tab = (float*)ws;
  float*        qtab  = (float*)(ws + ((size_t)64 << 10));
  unsigned int* kvS   = (unsigned int*)(ws + ((size_t)1 << 20));
  float*        qpart = (float*)(ws + ((size_t)32 << 20));
  float*        spart = (float*)(ws + ((size_t)48 << 20));

  hipLaunchKernelGGL(msa_k1a, dim3(1024), dim3(256), 0, stream,
                     m, mask, lng, lnb, Wk, Wv, kvS, qpart);
  hipLaunchKernelGGL(msa_k1b, dim3(256), dim3(64), 0, stream,
                     lnb, Wq, qpart, qtab);
  hipLaunchKernelGGL(msa_k1c, dim3(1024), dim3(256), 0, stream,
                     kvS, qtab, spart);
  hipLaunchKernelGGL(msa_k1d, dim3(256), dim3(64), 0, stream,
                     spart, o_tab);
  hipLaunchKernelGGL(msa_k2, dim3(2048), dim3(256), 0, stream,
                     m, lng, lnb, Wg, bg, Wo, bo, o_tab, out);
}

// Round 6
// 317.080 us; speedup vs baseline: 1.0535x; 1.0535x over previous
//
#include <hip/hip_runtime.h>

#define I_LEN 1024

__device__ __forceinline__ float bf2f(unsigned int lo16) {
  unsigned int u = lo16 << 16;
  float f; __builtin_memcpy(&f, &u, 4); return f;
}
__device__ __forceinline__ unsigned int f2bf(float f) {
  unsigned int u; __builtin_memcpy(&u, &f, 4);
  return (u + 0x7FFFu + ((u >> 16) & 1u)) >> 16;  // RNE
}

// K1: block b handles columns 2b..2b+1. 1024 threads: col = t&1, r = t>>1.
// R0-proven fused structure (80 us) with ONE change: 2 cols/block instead of
// 4 -> LDS 34 KB -> TWO blocks/CU co-resident (grid 512, launch_bounds
// (1024,8) caps VGPR at 64). One block's phase-2 VALU/exp work overlaps the
// other block's phase-1 global-load latency; R0 measured Occupancy 35%
// (1 block/CU, no overlap).
__global__ __launch_bounds__(1024, 8) void msa_k1(
    const float* __restrict__ m, const float* __restrict__ mask,
    const float* __restrict__ lng, const float* __restrict__ lnb,
    const float* __restrict__ Wq, const float* __restrict__ Wk,
    const float* __restrict__ Wv, float* __restrict__ o_tab)
{
  __shared__ unsigned int kvs[4096 * 2];   // 32 KB, idx = s*2+col
  __shared__ float red[16][2][16];         // [wave][col][quantity]
  __shared__ float fin[2][9];
  __shared__ float qtab[2][8];

  const int t    = threadIdx.x;
  const int col  = t & 1;
  const int r    = t >> 1;       // 0..511
  const int lane = t & 63;
  const int wave = t >> 6;
  const int icol = blockIdx.x * 2 + col;

  // uniform scalars (SGPR-sourced weights)
  float swk = 0.f, swv = 0.f, kb = 0.f, vb = 0.f;
#pragma unroll
  for (int c = 0; c < 8; ++c) {
    swk = fmaf(lng[c], Wk[c], swk);  swv = fmaf(lng[c], Wv[c], swv);
    kb  = fmaf(lnb[c], Wk[c], kb);   vb  = fmaf(lnb[c], Wv[c], vb);
  }

  unsigned int mb = 0;               // 8 mask bits (register)
  float qnx[8] = {0,0,0,0,0,0,0,0};  // sum over s of (gamma*xhat)_c * mk
  float qd = 0.0f;                   // sum over s of mk

  // ---- pass 1: LN, k/v -> LDS, pooled-q partials ----
#pragma unroll 2
  for (int j = 0; j < 8; ++j) {
    const int s = r + 512 * j;
    const float4* mp = (const float4*)(m + (size_t)(s * I_LEN + icol) * 8);
    float4 lo = mp[0], hi = mp[1];
    const float mk = mask[s * I_LEN + icol];
    float x[8] = {lo.x, lo.y, lo.z, lo.w, hi.x, hi.y, hi.z, hi.w};
    float su = 0.f, s2 = 0.f;
#pragma unroll
    for (int c = 0; c < 8; ++c) { su += x[c]; s2 = fmaf(x[c], x[c], s2); }
    const float mu   = su * 0.125f;
    const float var  = s2 * 0.125f - mu * mu;
    const float rstd = rsqrtf(var + 1e-5f);
    float dk = 0.f, dv = 0.f;
#pragma unroll
    for (int c = 0; c < 8; ++c) {
      const float xg = x[c] * lng[c];       // gamma fold (SGPR mult)
      dk = fmaf(xg, Wk[c], dk);
      dv = fmaf(xg, Wv[c], dv);
      x[c] = xg;
    }
    const float kk  = fmaf(rstd, fmaf(-mu, swk, dk), kb);
    const float vv  = fmaf(rstd, fmaf(-mu, swv, dv), vb);
    const float mr  = mk * rstd;
    const float mmr = -mu * mr;
#pragma unroll
    for (int c = 0; c < 8; ++c)
      qnx[c] = fmaf(x[c], mr, fmaf(lng[c], mmr, qnx[c]));
    qd += mk;
    kvs[s * 2 + col] = (f2bf(kk) << 16) | f2bf(vv);
    mb |= (mk > 0.5f ? 1u : 0u) << j;
  }

  // ---- reduce pooled-q partials over the 512 threads of each col ----
#pragma unroll
  for (int q = 0; q < 9; ++q) {
    float x = (q < 8) ? qnx[q] : qd;
#pragma unroll
    for (int off = 2; off <= 32; off <<= 1) x += __shfl_xor(x, off, 64);
    if (lane < 2) red[wave][lane][q] = x;
  }
  __syncthreads();
  if (t < 18) {
    int cc = t / 9, q = t - cc * 9;
    float s = 0.f;
#pragma unroll
    for (int w = 0; w < 16; ++w) s += red[w][cc][q];
    fin[cc][q] = s;
  }
  __syncthreads();
  if (t < 16) {
    int cc = t >> 3, h = t & 7;
    const float invd = 1.0f / (fin[cc][8] + 1e-5f);
    float qv = 0.f;
#pragma unroll
    for (int c = 0; c < 8; ++c) {
      const float qn = fmaf(lnb[c], fin[cc][8], fin[cc][c]);  // + beta*sum(mk)
      qv = fmaf(qn * invd, Wq[c * 8 + h], qv);   // c_h^-0.5 == 1
    }
    qtab[cc][h] = qv;
  }
  __syncthreads();

  float qh[8];
#pragma unroll
  for (int h = 0; h < 8; ++h) qh[h] = qtab[col][h];

  // ---- pass 2: sum exp, sum exp*v (logits O(1): no max-subtraction) ----
  float se[8] = {0,0,0,0,0,0,0,0};
  float sv[8] = {0,0,0,0,0,0,0,0};
#pragma unroll 4
  for (int j = 0; j < 8; ++j) {
    const unsigned int w = kvs[(r + 512 * j) * 2 + col];
    const float kk = bf2f(w >> 16);
    const float vv = bf2f(w & 0xFFFFu);
    const float on = ((mb >> j) & 1u) ? 1.0f : 0.0f;
#pragma unroll
    for (int h = 0; h < 8; ++h) {
      const float e = __expf(qh[h] * kk) * on;
      se[h] += e;
      sv[h] = fmaf(e, vv, sv[h]);
    }
  }
#pragma unroll
  for (int q = 0; q < 16; ++q) {
    float x = (q < 8) ? se[q] : sv[q - 8];
#pragma unroll
    for (int off = 2; off <= 32; off <<= 1) x += __shfl_xor(x, off, 64);
    if (lane < 2) red[wave][lane][q] = x;
  }
  __syncthreads();
  if (t < 16) {
    int cc = t >> 3, h = t & 7;
    float a = 0.f, b = 0.f;
#pragma unroll
    for (int w = 0; w < 16; ++w) { a += red[w][cc][h]; b += red[w][cc][8 + h]; }
    o_tab[(blockIdx.x * 2 + cc) * 8 + h] = b / a;
  }
}

// K2: R0-proven streaming pass (67 us) restored verbatim -- normal float4
// stores (nontemporal regressed: R4/R5 measured 83/78.5 us), no forced load
// batching, compiler's own unroll-2 schedule -- plus ONE change kept from R5:
// sigmoid via v_rcp instead of the exact-division sequence (VALUBusy 67->57%).
__global__ __launch_bounds__(256, 2) void msa_k2(
    const float* __restrict__ m,
    const float* __restrict__ lng, const float* __restrict__ lnb,
    const float* __restrict__ Wg, const float* __restrict__ bg,
    const float* __restrict__ Wo, const float* __restrict__ bo,
    const float* __restrict__ o_tab, float* __restrict__ out)
{
  const int tid = blockIdx.x * 256 + threadIdx.x;   // 524288 threads
  const int i = tid & (I_LEN - 1);                  // same for all 8 points

  // uniform derived vectors (SGPR-sourced weights)
  float sgv[8], tbv[8];
#pragma unroll
  for (int h = 0; h < 8; ++h) {
    float s = 0.f, tb = bg[h];
#pragma unroll
    for (int c = 0; c < 8; ++c) {
      s  = fmaf(lng[c], Wg[c * 8 + h], s);
      tb = fmaf(lnb[c], Wg[c * 8 + h], tb);
    }
    sgv[h] = s; tbv[h] = tb;
  }

  const float4* op = (const float4*)(o_tab + i * 8);
  const float4 o1 = op[0], o2 = op[1];
  const float A[8] = {o1.x, o1.y, o1.z, o1.w, o2.x, o2.y, o2.z, o2.w};

#pragma unroll 2
  for (int q = 0; q < 8; ++q) {
    const size_t p = (size_t)tid + (size_t)q * 524288;
    const float4* mp = (const float4*)(m + p * 8);
    const float4 lo = mp[0], hi = mp[1];
    float x[8] = {lo.x, lo.y, lo.z, lo.w, hi.x, hi.y, hi.z, hi.w};
    float su = 0.f, s2 = 0.f;
#pragma unroll
    for (int c = 0; c < 8; ++c) { su += x[c]; s2 = fmaf(x[c], x[c], s2); }
    const float mu   = su * 0.125f;
    const float var  = s2 * 0.125f - mu * mu;
    const float rstd = rsqrtf(var + 1e-5f);
#pragma unroll
    for (int c = 0; c < 8; ++c) x[c] *= lng[c];     // gamma fold (SGPR mult)
    float acc[8];
#pragma unroll
    for (int c = 0; c < 8; ++c) acc[c] = bo[c];     // SGPR broadcast
#pragma unroll
    for (int h = 0; h < 8; ++h) {
      float d = 0.f;
#pragma unroll
      for (int c = 0; c < 8; ++c) d = fmaf(x[c], Wg[c * 8 + h], d);  // SGPR wgt
      const float gl = fmaf(rstd, fmaf(-mu, sgv[h], d), tbv[h]);
      const float gv = A[h] * __builtin_amdgcn_rcpf(1.0f + __expf(-gl));
#pragma unroll
      for (int c = 0; c < 8; ++c) acc[c] = fmaf(gv, Wo[h * 8 + c], acc[c]);
    }
    float4* outp = (float4*)(out + p * 8);
    outp[0] = make_float4(acc[0], acc[1], acc[2], acc[3]);
    outp[1] = make_float4(acc[4], acc[5], acc[6], acc[7]);
  }
}

extern "C" void kernel_launch(void* const* d_in, const int* in_sizes, int n_in,
                              void* d_out, int out_size, void* d_ws, size_t ws_size,
                              hipStream_t stream) {
  const float* m    = (const float*)d_in[0];
  const float* mask = (const float*)d_in[1];
  const float* lng  = (const float*)d_in[2];
  const float* lnb  = (const float*)d_in[3];
  const float* Wq   = (const float*)d_in[4];
  const float* Wk   = (const float*)d_in[5];
  const float* Wv   = (const float*)d_in[6];
  const float* Wg   = (const float*)d_in[7];
  const float* bg   = (const float*)d_in[8];
  const float* Wo   = (const float*)d_in[9];
  const float* bo   = (const float*)d_in[10];
  float* out   = (float*)d_out;
  float* o_tab = (float*)d_ws;   // 1024*8 floats = 32 KB

  hipLaunchKernelGGL(msa_k1, dim3(512), dim3(1024), 0, stream,
                     m, mask, lng, lnb, Wq, Wk, Wv, o_tab);
  hipLaunchKernelGGL(msa_k2, dim3(2048), dim3(256), 0, stream,
                     m, lng, lnb, Wg, bg, Wo, bo, o_tab, out);
}